// Round 5
// baseline (552.178 us; speedup 1.0000x reference)
//
#include <hip/hip_runtime.h>
#include <hip/hip_fp16.h>

#define NN 50000
#define EE 800000
#define LL 3
#define HH 4
#define CC 16
#define DD 64
#define GG 512
#define GRAPH_DIM 128

// ---------------------------------------------------------------------------
// utility: zero int / float ranges
// ---------------------------------------------------------------------------
__global__ void zero_i32(int* p, int n) {
    int i = blockIdx.x * blockDim.x + threadIdx.x;
    if (i < n) p[i] = 0;
}
__global__ void zero_f32(float* p, int n) {
    int i = blockIdx.x * blockDim.x + threadIdx.x;
    if (i < n) p[i] = 0.f;
}

// ---------------------------------------------------------------------------
// CSR build: histogram of dst, exclusive scan, scatter (src, attr) by dst
// ---------------------------------------------------------------------------
__global__ void hist_kernel(const int* __restrict__ dst, int* __restrict__ counts) {
    int e = blockIdx.x * blockDim.x + threadIdx.x;
    if (e < EE) atomicAdd(&counts[dst[e]], 1);
}

__global__ __launch_bounds__(1024) void scan_kernel(const int* __restrict__ counts,
                                                    int* __restrict__ row_ptr,
                                                    int* __restrict__ writepos) {
    __shared__ int wsum[16];
    int t = threadIdx.x, lane = t & 63, wid = t >> 6;
    int base = 0;
    for (int start = 0; start < NN; start += 1024) {
        int idx = start + t;
        int val = (idx < NN) ? counts[idx] : 0;
        int x = val;
        #pragma unroll
        for (int o = 1; o < 64; o <<= 1) {
            int y = __shfl_up(x, o);
            if (lane >= o) x += y;
        }
        if (lane == 63) wsum[wid] = x;
        __syncthreads();
        if (wid == 0) {
            int s = (lane < 16) ? wsum[lane] : 0;
            #pragma unroll
            for (int o = 1; o < 16; o <<= 1) {
                int y = __shfl_up(s, o);
                if (lane >= o) s += y;
            }
            if (lane < 16) wsum[lane] = s;
        }
        __syncthreads();
        int excl = x - val + base + (wid > 0 ? wsum[wid - 1] : 0);
        if (idx < NN) { row_ptr[idx] = excl; writepos[idx] = excl; }
        int total = wsum[15];
        __syncthreads();
        base += total;
    }
    if (t == 0) row_ptr[NN] = base;
}

__global__ void scatter_kernel(const int* __restrict__ ei, const float* __restrict__ attr,
                               int* __restrict__ writepos,
                               int* __restrict__ src_s, float* __restrict__ attr_s) {
    int e = blockIdx.x * blockDim.x + threadIdx.x;
    if (e < EE) {
        int s = ei[e];
        int d = ei[EE + e];
        int p = atomicAdd(&writepos[d], 1);
        src_s[p] = s;
        attr_s[p] = attr[e];
    }
}

// ---------------------------------------------------------------------------
// fused node GEMM: q = h@Wq+bq (f32) ; sk = h@Ws+bs (f32)
// kvh[node*64 + j] = half2( (h@Wk+bk)_j , (h@Wv+bv)_j )
// k/v staged in LDS, then packed half2 DWORD stores (coalesced) — avoids
// 6.4M sub-dword global stores per dispatch.
// ---------------------------------------------------------------------------
__global__ __launch_bounds__(256) void node_gemm(
    const float* __restrict__ hx,
    const float* __restrict__ Wq, const float* __restrict__ bq,
    const float* __restrict__ Wk, const float* __restrict__ bk,
    const float* __restrict__ Wv, const float* __restrict__ bv,
    const float* __restrict__ Ws, const float* __restrict__ bs,
    float* __restrict__ q, __half* __restrict__ kvh, float* __restrict__ sk)
{
    __shared__ float xs[32 * 64];
    __shared__ float kb[32 * 64];
    __shared__ float vb[32 * 64];
    int t = threadIdx.x;
    int node0 = blockIdx.x * 32;

    const float4* src4 = (const float4*)(hx + (size_t)node0 * 64);
    float4* dst4 = (float4*)xs;
    #pragma unroll
    for (int r = 0; r < 2; ++r) {
        int i4 = t + r * 256;
        int node = node0 + (i4 >> 4);
        float4 val = make_float4(0.f, 0.f, 0.f, 0.f);
        if (node < NN) val = src4[i4];
        dst4[i4] = val;
    }
    __syncthreads();

    int mat = t >> 6, j = t & 63;
    const float* W = (mat == 0) ? Wq : (mat == 1) ? Wk : (mat == 2) ? Wv : Ws;
    const float* B = (mat == 0) ? bq : (mat == 1) ? bk : (mat == 2) ? bv : bs;

    float wcol[64];
    #pragma unroll
    for (int i = 0; i < 64; ++i) wcol[i] = W[i * 64 + j];
    float bj = B[j];

    for (int n = 0; n < 32; ++n) {
        int node = node0 + n;
        if (node >= NN) break;
        float acc = bj;
        const float4* xr = (const float4*)(xs + n * 64);
        #pragma unroll
        for (int i4 = 0; i4 < 16; ++i4) {
            float4 xv = xr[i4];
            acc = fmaf(xv.x, wcol[4 * i4 + 0], acc);
            acc = fmaf(xv.y, wcol[4 * i4 + 1], acc);
            acc = fmaf(xv.z, wcol[4 * i4 + 2], acc);
            acc = fmaf(xv.w, wcol[4 * i4 + 3], acc);
        }
        size_t idx = (size_t)node * 64 + j;
        if (mat == 0)      q[idx]  = acc;
        else if (mat == 3) sk[idx] = acc;
        else if (mat == 1) kb[n * 64 + j] = acc;
        else               vb[n * 64 + j] = acc;
    }
    __syncthreads();

    // cooperative packed kv store: 2048 dwords by 256 threads, coalesced
    unsigned* kvd = (unsigned*)kvh;
    #pragma unroll
    for (int r = 0; r < 8; ++r) {
        int idx = t + r * 256;            // 0..2047
        int n = idx >> 6, j2 = idx & 63;
        int nd = node0 + n;
        if (nd < NN) {
            __half2 hv = __halves2half2(__float2half_rn(kb[idx]),
                                        __float2half_rn(vb[idx]));
            kvd[(size_t)nd * 64 + j2] = __builtin_bit_cast(unsigned, hv);
        }
    }
}

// ---------------------------------------------------------------------------
// persistent node-centric attention, cross-node software pipeline:
//   lane = head*16 + edge_slot;  waves grid-stride over nodes.
//   Depth: row_ptr 3-ahead, src/attr 2-ahead, q/sk 1-ahead,
//          kv chunk-0 1-ahead (full iteration of latency cover);
//          kv chunk-1 in-iteration (covered by qw + chunk-0 consume).
//   We/We[lane] reloaded per iteration (L1-resident broadcast) to keep
//   VGPR under the 128 occupancy step.
// ---------------------------------------------------------------------------
static __device__ __forceinline__ float2 h2f2(unsigned u) {
    __half2 h = __builtin_bit_cast(__half2, u);
    return __half22float2(h);
}

// clamp edge index e into [p0, p1-1] and [0, EE-1] (mask handles validity)
static __device__ __forceinline__ int cidx(int e, int p0, int p1) {
    int hi = max(p1 - 1, p0);
    int i = min(e, hi);
    return min(i, EE - 1);
}

static __device__ __forceinline__ void chunk16(
    uint4 u0, uint4 u1, uint4 u2, uint4 u3,
    float4 q0, float4 q1, float4 q2, float4 q3,
    float a, float qw, int e, int p1,
    float* accv, float& den, float& saw)
{
    float vt[16];
    float sc = 0.f;
    float2 f;
    f = h2f2(u0.x); sc = fmaf(q0.x, f.x, sc); vt[0]  = f.y;
    f = h2f2(u0.y); sc = fmaf(q0.y, f.x, sc); vt[1]  = f.y;
    f = h2f2(u0.z); sc = fmaf(q0.z, f.x, sc); vt[2]  = f.y;
    f = h2f2(u0.w); sc = fmaf(q0.w, f.x, sc); vt[3]  = f.y;
    f = h2f2(u1.x); sc = fmaf(q1.x, f.x, sc); vt[4]  = f.y;
    f = h2f2(u1.y); sc = fmaf(q1.y, f.x, sc); vt[5]  = f.y;
    f = h2f2(u1.z); sc = fmaf(q1.z, f.x, sc); vt[6]  = f.y;
    f = h2f2(u1.w); sc = fmaf(q1.w, f.x, sc); vt[7]  = f.y;
    f = h2f2(u2.x); sc = fmaf(q2.x, f.x, sc); vt[8]  = f.y;
    f = h2f2(u2.y); sc = fmaf(q2.y, f.x, sc); vt[9]  = f.y;
    f = h2f2(u2.z); sc = fmaf(q2.z, f.x, sc); vt[10] = f.y;
    f = h2f2(u2.w); sc = fmaf(q2.w, f.x, sc); vt[11] = f.y;
    f = h2f2(u3.x); sc = fmaf(q3.x, f.x, sc); vt[12] = f.y;
    f = h2f2(u3.y); sc = fmaf(q3.y, f.x, sc); vt[13] = f.y;
    f = h2f2(u3.z); sc = fmaf(q3.z, f.x, sc); vt[14] = f.y;
    f = h2f2(u3.w); sc = fmaf(q3.w, f.x, sc); vt[15] = f.y;

    float w = __expf(fmaf(a, qw, sc) * 0.25f);
    if (e >= p1) w = 0.f;
    den += w;
    saw = fmaf(w, a, saw);
    #pragma unroll
    for (int j = 0; j < 16; ++j) accv[j] = fmaf(w, vt[j], accv[j]);
}

#define ATTN_BLOCKS 2048

__global__ __launch_bounds__(256) void node_attn(
    const float* __restrict__ q, const __half* __restrict__ kvh,
    const float* __restrict__ sk, const float* __restrict__ We,
    const int* __restrict__ row_ptr, const int* __restrict__ src_s,
    const float* __restrict__ attr_s,
    float* __restrict__ out, int do_relu, int do_pool,
    const int* __restrict__ batch,
    float* __restrict__ gsum, float* __restrict__ gcnt)
{
    __shared__ float lds[4 * 16 * 68];
    int wid   = threadIdx.x >> 6;
    int lane  = threadIdx.x & 63;
    int eslot = lane & 15;
    int head  = lane >> 4;

    const int NW = ATTN_BLOCKS * 4;
    int node = blockIdx.x * 4 + wid;
    if (node >= NN) return;

    float* buf = lds + wid * (16 * 68);
    const __half* kvbase = kvh + head * 32;
    const float4* wep = (const float4*)(We + head * 16);

    // ---- prologue: fill 3-deep pipeline ----
    int n1 = node + NW;     int n1c = (n1 < NN) ? n1 : node;
    int n2 = node + 2 * NW; int n2c = (n2 < NN) ? n2 : node;
    int p0c = row_ptr[node], p1c = row_ptr[node + 1];
    int p0n = row_ptr[n1c],  p1n = row_ptr[n1c + 1];
    int p0n2 = row_ptr[n2c], p1n2 = row_ptr[n2c + 1];

    int i0 = cidx(p0c + eslot, p0c, p1c);
    int i1 = cidx(p0c + 16 + eslot, p0c, p1c);
    int   s0c = src_s[i0]; float a0c = attr_s[i0];
    int   s1c = src_s[i1]; float a1c = attr_s[i1];
    int j0 = cidx(p0n + eslot, p0n, p1n);
    int j1 = cidx(p0n + 16 + eslot, p0n, p1n);
    int   s0n = src_s[j0]; float a0n = attr_s[j0];
    int   s1n = src_s[j1]; float a1n = attr_s[j1];

    const float4* qp = (const float4*)(q + (size_t)node * 64 + head * 16);
    float4 qc0 = qp[0], qc1 = qp[1], qc2 = qp[2], qc3 = qp[3];
    float skc = sk[(size_t)node * 64 + lane];

    // kv chunk-0 for first node
    const uint4* kvp0 = (const uint4*)(kvbase + (size_t)s0c * 128);
    uint4 u0 = kvp0[0], u1 = kvp0[1], u2 = kvp0[2], u3 = kvp0[3];

    for (;;) {
        int nx1 = node + NW;
        int nx3 = node + 3 * NW;
        int nx1c = (nx1 < NN) ? nx1 : node;
        int nx3c = (nx3 < NN) ? nx3 : node;

        // ---- issue phase (all independent of current compute) ----
        // kv chunk-1 (current node)
        const uint4* kvb = (const uint4*)(kvbase + (size_t)s1c * 128);
        uint4 x0 = kvb[0], x1 = kvb[1], x2 = kvb[2], x3 = kvb[3];
        // kv chunk-0 for NEXT node (full iteration of cover)
        const uint4* kvn = (const uint4*)(kvbase + (size_t)s0n * 128);
        uint4 un0 = kvn[0], un1 = kvn[1], un2 = kvn[2], un3 = kvn[3];
        // row_ptr (n+3)
        int p0n3 = row_ptr[nx3c], p1n3 = row_ptr[nx3c + 1];
        // src/attr (n+2)
        int k0 = cidx(p0n2 + eslot, p0n2, p1n2);
        int k1 = cidx(p0n2 + 16 + eslot, p0n2, p1n2);
        int   s0n2 = src_s[k0]; float a0n2 = attr_s[k0];
        int   s1n2 = src_s[k1]; float a1n2 = attr_s[k1];
        // q/sk (n+1)
        const float4* qpn = (const float4*)(q + (size_t)nx1c * 64 + head * 16);
        float4 qn0 = qpn[0], qn1 = qpn[1], qn2 = qpn[2], qn3 = qpn[3];
        float skn = sk[(size_t)nx1c * 64 + lane];
        // We slices (L1-resident broadcast, reloaded to save VGPRs)
        float4 w0 = wep[0], w1 = wep[1], w2 = wep[2], w3 = wep[3];
        float wec = We[lane];

        // ---- compute phase ----
        float qw = qc0.x * w0.x;
        qw = fmaf(qc0.y, w0.y, qw); qw = fmaf(qc0.z, w0.z, qw); qw = fmaf(qc0.w, w0.w, qw);
        qw = fmaf(qc1.x, w1.x, qw); qw = fmaf(qc1.y, w1.y, qw); qw = fmaf(qc1.z, w1.z, qw); qw = fmaf(qc1.w, w1.w, qw);
        qw = fmaf(qc2.x, w2.x, qw); qw = fmaf(qc2.y, w2.y, qw); qw = fmaf(qc2.z, w2.z, qw); qw = fmaf(qc2.w, w2.w, qw);
        qw = fmaf(qc3.x, w3.x, qw); qw = fmaf(qc3.y, w3.y, qw); qw = fmaf(qc3.z, w3.z, qw); qw = fmaf(qc3.w, w3.w, qw);

        float accv[16];
        #pragma unroll
        for (int j = 0; j < 16; ++j) accv[j] = 0.f;
        float den = 0.f, saw = 0.f;

        chunk16(u0, u1, u2, u3, qc0, qc1, qc2, qc3,
                a0c, qw, p0c + eslot, p1c, accv, den, saw);
        chunk16(x0, x1, x2, x3, qc0, qc1, qc2, qc3,
                a1c, qw, p0c + 16 + eslot, p1c, accv, den, saw);

        // remainder chunks (deg > 32; rare for Poisson(16))
        #pragma unroll 1
        for (int p = p0c + 32; p < p1c; p += 16) {
            int e = p + eslot;
            int i = cidx(e, p0c, p1c);
            int s = src_s[i];
            float a = attr_s[i];
            const uint4* kr = (const uint4*)(kvbase + (size_t)s * 128);
            uint4 r0 = kr[0], r1 = kr[1], r2 = kr[2], r3 = kr[3];
            chunk16(r0, r1, r2, r3, qc0, qc1, qc2, qc3,
                    a, qw, e, p1c, accv, den, saw);
        }

        // den/saw: reduce across the 16 edge-lanes of this head
        den += __shfl_xor(den, 1); den += __shfl_xor(den, 2);
        den += __shfl_xor(den, 4); den += __shfl_xor(den, 8);
        saw += __shfl_xor(saw, 1); saw += __shfl_xor(saw, 2);
        saw += __shfl_xor(saw, 4); saw += __shfl_xor(saw, 8);

        // acc transpose: (head,edge) partials -> per-channel totals via LDS
        float4* bw = (float4*)(buf + eslot * 68 + head * 16);
        bw[0] = make_float4(accv[0],  accv[1],  accv[2],  accv[3]);
        bw[1] = make_float4(accv[4],  accv[5],  accv[6],  accv[7]);
        bw[2] = make_float4(accv[8],  accv[9],  accv[10], accv[11]);
        bw[3] = make_float4(accv[12], accv[13], accv[14], accv[15]);
        float tot = 0.f;
        #pragma unroll
        for (int e2 = 0; e2 < 16; ++e2) tot += buf[e2 * 68 + lane];

        float o = fmaf(saw, wec, tot) / (den + 1e-16f) + skc;
        if (do_relu) o = fmaxf(o, 0.f);
        out[(size_t)node * 64 + lane] = o;

        if (do_pool) {
            int b = batch[node];
            atomicAdd(&gsum[(size_t)b * 64 + lane], o);
            if (lane == 0) atomicAdd(&gcnt[b], 1.f);
        }

        // ---- rotate pipeline ----
        node = nx1;
        if (node >= NN) break;
        p0c = p0n;  p1c = p1n;
        p0n = p0n2; p1n = p1n2;
        p0n2 = p0n3; p1n2 = p1n3;
        s0c = s0n;  a0c = a0n;  s1c = s1n;  a1c = a1n;
        s0n = s0n2; a0n = a0n2; s1n = s1n2; a1n = a1n2;
        qc0 = qn0; qc1 = qn1; qc2 = qn2; qc3 = qn3;
        skc = skn;
        u0 = un0; u1 = un1; u2 = un2; u3 = un3;
    }
}

// ---------------------------------------------------------------------------
// mean-pool finalize + 3-layer MLP head; one block (128 thr) per graph
// ---------------------------------------------------------------------------
__global__ __launch_bounds__(128) void pool_mlp(
    const float* __restrict__ gsum, const float* __restrict__ gcnt,
    const float* __restrict__ W1, const float* __restrict__ b1,
    const float* __restrict__ W2, const float* __restrict__ b2,
    const float* __restrict__ W3, const float* __restrict__ b3,
    float* __restrict__ out)
{
    __shared__ float g[64];
    __shared__ float h1s[64];
    __shared__ float h2s[16];
    int b = blockIdx.x, t = threadIdx.x;

    if (t < 64) {
        float c = gcnt[b];
        g[t] = gsum[(size_t)b * 64 + t] / fmaxf(c, 1.f);
    }
    __syncthreads();
    if (t < 64) {
        float a = b1[t];
        #pragma unroll
        for (int i = 0; i < 64; ++i) a = fmaf(g[i], W1[i * 64 + t], a);
        h1s[t] = fmaxf(a, 0.f);
    }
    __syncthreads();
    if (t < 16) {
        float a = b2[t];
        #pragma unroll
        for (int i = 0; i < 64; ++i) a = fmaf(h1s[i], W2[i * 16 + t], a);
        h2s[t] = fmaxf(a, 0.f);
    }
    __syncthreads();
    float a = b3[t];
    #pragma unroll
    for (int i = 0; i < 16; ++i) a = fmaf(h2s[i], W3[i * 128 + t], a);
    out[(size_t)b * 128 + t] = a;
}

// ---------------------------------------------------------------------------
extern "C" void kernel_launch(void* const* d_in, const int* in_sizes, int n_in,
                              void* d_out, int out_size, void* d_ws, size_t ws_size,
                              hipStream_t stream) {
    const float* x         = (const float*)d_in[0];
    const float* edge_attr = (const float*)d_in[1];
    const int*   edge_index= (const int*)d_in[2];
    const int*   batch     = (const int*)d_in[3];
    const float* Wq   = (const float*)d_in[4];
    const float* bq   = (const float*)d_in[5];
    const float* Wk   = (const float*)d_in[6];
    const float* bk   = (const float*)d_in[7];
    const float* Wv   = (const float*)d_in[8];
    const float* bv   = (const float*)d_in[9];
    const float* We   = (const float*)d_in[10];
    const float* Wsk  = (const float*)d_in[11];
    const float* bsk  = (const float*)d_in[12];
    const float* W1   = (const float*)d_in[13];
    const float* b1   = (const float*)d_in[14];
    const float* W2   = (const float*)d_in[15];
    const float* b2   = (const float*)d_in[16];
    const float* W3   = (const float*)d_in[17];
    const float* b3   = (const float*)d_in[18];

    float* out        = (float*)d_out;
    float* node_emb   = out;                         // N*64
    float* graph_feat = out + (size_t)NN * 64;       // G*128

    float* wsf    = (float*)d_ws;
    float* q      = wsf;
    float* kvf    = q    + (size_t)NN * 64;          // N*64 dwords: packed half2(k,v)
    float* skp    = kvf  + (size_t)NN * 64;
    float* h      = skp  + (size_t)NN * 64;
    float* attr_s = h    + (size_t)NN * 64;
    int*   src_s  = (int*)(attr_s + EE);
    int*   row_ptr= src_s + EE;
    int*   wpos   = row_ptr + (NN + 1);
    float* gsum   = (float*)(wpos + NN);
    float* gcnt   = gsum + (size_t)GG * 64;
    __half* kvh   = (__half*)kvf;

    // ---- CSR build (dst-sorted edges); reused by all 3 layers ----
    zero_i32<<<(NN + 255) / 256, 256, 0, stream>>>(wpos, NN);
    zero_f32<<<(GG * 64 + GG + 255) / 256, 256, 0, stream>>>(gsum, GG * 64 + GG);
    hist_kernel<<<(EE + 255) / 256, 256, 0, stream>>>(edge_index + EE, wpos);
    scan_kernel<<<1, 1024, 0, stream>>>(wpos, row_ptr, wpos);
    scatter_kernel<<<(EE + 255) / 256, 256, 0, stream>>>(edge_index, edge_attr,
                                                         wpos, src_s, attr_s);

    int gemm_grid = (NN + 31) / 32;

    const float* layer_in = x;
    for (int l = 0; l < LL; ++l) {
        const float* Wq_l = Wq + (size_t)l * 64 * 64;
        const float* Wk_l = Wk + (size_t)l * 64 * 64;
        const float* Wv_l = Wv + (size_t)l * 64 * 64;
        const float* Ws_l = Wsk + (size_t)l * 64 * 64;
        const float* bq_l = bq + (size_t)l * 64;
        const float* bk_l = bk + (size_t)l * 64;
        const float* bv_l = bv + (size_t)l * 64;
        const float* bs_l = bsk + (size_t)l * 64;
        const float* We_l = We + (size_t)l * 64;

        node_gemm<<<gemm_grid, 256, 0, stream>>>(layer_in,
            Wq_l, bq_l, Wk_l, bk_l, Wv_l, bv_l, Ws_l, bs_l,
            q, kvh, skp);

        int last = (l == LL - 1);
        float* dst_h = last ? node_emb : h;
        node_attn<<<ATTN_BLOCKS, 256, 0, stream>>>(q, kvh, skp, We_l,
            row_ptr, src_s, attr_s,
            dst_h, /*relu=*/!last, /*pool=*/last,
            batch, gsum, gcnt);

        layer_in = h;
    }

    pool_mlp<<<GG, 128, 0, stream>>>(gsum, gcnt, W1, b1, W2, b2, W3, b3, graph_feat);
}

// Round 6
// 496.366 us; speedup vs baseline: 1.1124x; 1.1124x over previous
//
#include <hip/hip_runtime.h>
#include <hip/hip_fp16.h>

#define NN 50000
#define EE 800000
#define LL 3
#define HH 4
#define CC 16
#define DD 64
#define GG 512
#define GRAPH_DIM 128
#define SCAN_B 196   // ceil(NN/256)

// ---------------------------------------------------------------------------
// utility: zero int / float ranges
// ---------------------------------------------------------------------------
__global__ void zero_i32(int* p, int n) {
    int i = blockIdx.x * blockDim.x + threadIdx.x;
    if (i < n) p[i] = 0;
}
__global__ void zero_f32(float* p, int n) {
    int i = blockIdx.x * blockDim.x + threadIdx.x;
    if (i < n) p[i] = 0.f;
}

// ---------------------------------------------------------------------------
// CSR build: histogram of dst, 3-stage parallel exclusive scan, scatter
// ---------------------------------------------------------------------------
__global__ void hist_kernel(const int* __restrict__ dst, int* __restrict__ counts) {
    int e = blockIdx.x * blockDim.x + threadIdx.x;
    if (e < EE) atomicAdd(&counts[dst[e]], 1);
}

// stage 1: per-block (256 elems) sums
__global__ __launch_bounds__(256) void scan_partial(const int* __restrict__ counts,
                                                    int* __restrict__ bsum) {
    __shared__ int ws[4];
    int b = blockIdx.x, t = threadIdx.x, lane = t & 63, wid = t >> 6;
    int idx = b * 256 + t;
    int x = (idx < NN) ? counts[idx] : 0;
    #pragma unroll
    for (int o = 1; o < 64; o <<= 1) x += __shfl_xor(x, o);
    if (lane == 0) ws[wid] = x;
    __syncthreads();
    if (t == 0) bsum[b] = ws[0] + ws[1] + ws[2] + ws[3];
}

// stage 2: one block scans the 196 block sums (Hillis-Steele over 256 slots)
__global__ __launch_bounds__(256) void scan_tops(const int* __restrict__ bsum,
                                                 int* __restrict__ boff,
                                                 int* __restrict__ row_ptr) {
    __shared__ int tmp[2][256];
    int t = threadIdx.x;
    int v = (t < SCAN_B) ? bsum[t] : 0;
    tmp[0][t] = v;
    __syncthreads();
    int src = 0;
    for (int o = 1; o < 256; o <<= 1) {
        int val = tmp[src][t];
        if (t >= o) val += tmp[src][t - o];
        tmp[src ^ 1][t] = val;
        __syncthreads();
        src ^= 1;
    }
    if (t < SCAN_B) boff[t] = tmp[src][t] - v;   // exclusive
    if (t == 255) row_ptr[NN] = tmp[src][255];   // total = EE
}

// stage 3: local exclusive scan + block offset -> row_ptr & writepos
__global__ __launch_bounds__(256) void scan_final(const int* __restrict__ counts,
                                                  const int* __restrict__ boff,
                                                  int* __restrict__ row_ptr,
                                                  int* __restrict__ wpos) {
    __shared__ int ws[4];
    int b = blockIdx.x, t = threadIdx.x, lane = t & 63, wid = t >> 6;
    int idx = b * 256 + t;
    int v = (idx < NN) ? counts[idx] : 0;
    int x = v;
    #pragma unroll
    for (int o = 1; o < 64; o <<= 1) {
        int y = __shfl_up(x, o);
        if (lane >= o) x += y;
    }
    if (lane == 63) ws[wid] = x;
    __syncthreads();
    int add = boff[b];
    #pragma unroll
    for (int w = 0; w < 4; ++w) add += (w < wid) ? ws[w] : 0;
    int excl = x - v + add;
    if (idx < NN) { row_ptr[idx] = excl; wpos[idx] = excl; }
}

__global__ void scatter_kernel(const int* __restrict__ ei, const float* __restrict__ attr,
                               int* __restrict__ writepos,
                               int* __restrict__ src_s, float* __restrict__ attr_s) {
    int e = blockIdx.x * blockDim.x + threadIdx.x;
    if (e < EE) {
        int s = ei[e];
        int d = ei[EE + e];
        int p = atomicAdd(&writepos[d], 1);
        src_s[p] = s;
        attr_s[p] = attr[e];
    }
}

// ---------------------------------------------------------------------------
// fused node GEMM (R4 version — measured fastest): q = h@Wq+bq (f32);
// sk = h@Ws+bs (f32); kvh[node*64+j] = half2(k_j, v_j) via 2B half stores
// (k-wave / v-wave write disjoint halves of each dword).
// ---------------------------------------------------------------------------
__global__ __launch_bounds__(256) void node_gemm(
    const float* __restrict__ hx,
    const float* __restrict__ Wq, const float* __restrict__ bq,
    const float* __restrict__ Wk, const float* __restrict__ bk,
    const float* __restrict__ Wv, const float* __restrict__ bv,
    const float* __restrict__ Ws, const float* __restrict__ bs,
    float* __restrict__ q, __half* __restrict__ kvh, float* __restrict__ sk)
{
    __shared__ float xs[32 * 64];
    int t = threadIdx.x;
    int node0 = blockIdx.x * 32;

    const float4* src4 = (const float4*)(hx + (size_t)node0 * 64);
    float4* dst4 = (float4*)xs;
    #pragma unroll
    for (int r = 0; r < 2; ++r) {
        int i4 = t + r * 256;
        int node = node0 + (i4 >> 4);
        float4 val = make_float4(0.f, 0.f, 0.f, 0.f);
        if (node < NN) val = src4[i4];
        dst4[i4] = val;
    }
    __syncthreads();

    int mat = t >> 6, j = t & 63;
    const float* W = (mat == 0) ? Wq : (mat == 1) ? Wk : (mat == 2) ? Wv : Ws;
    const float* B = (mat == 0) ? bq : (mat == 1) ? bk : (mat == 2) ? bv : bs;

    float wcol[64];
    #pragma unroll
    for (int i = 0; i < 64; ++i) wcol[i] = W[i * 64 + j];
    float bj = B[j];

    for (int n = 0; n < 32; ++n) {
        int node = node0 + n;
        if (node >= NN) break;
        float acc = bj;
        const float4* xr = (const float4*)(xs + n * 64);
        #pragma unroll
        for (int i4 = 0; i4 < 16; ++i4) {
            float4 xv = xr[i4];
            acc = fmaf(xv.x, wcol[4 * i4 + 0], acc);
            acc = fmaf(xv.y, wcol[4 * i4 + 1], acc);
            acc = fmaf(xv.z, wcol[4 * i4 + 2], acc);
            acc = fmaf(xv.w, wcol[4 * i4 + 3], acc);
        }
        size_t idx = (size_t)node * 64 + j;
        if (mat == 0)      q[idx]  = acc;
        else if (mat == 3) sk[idx] = acc;
        else kvh[idx * 2 + (mat == 2)] = __float2half_rn(acc);
    }
}

// ---------------------------------------------------------------------------
// persistent node-centric attention, cross-node software pipeline (R5):
//   lane = head*16 + edge_slot;  waves grid-stride over nodes.
//   Depth: row_ptr 3-ahead, src/attr 2-ahead, q/sk 1-ahead,
//          kv chunk-0 1-ahead;  kv chunk-1 in-iteration.
// ---------------------------------------------------------------------------
static __device__ __forceinline__ float2 h2f2(unsigned u) {
    __half2 h = __builtin_bit_cast(__half2, u);
    return __half22float2(h);
}

static __device__ __forceinline__ int cidx(int e, int p0, int p1) {
    int hi = max(p1 - 1, p0);
    int i = min(e, hi);
    return min(i, EE - 1);
}

static __device__ __forceinline__ void chunk16(
    uint4 u0, uint4 u1, uint4 u2, uint4 u3,
    float4 q0, float4 q1, float4 q2, float4 q3,
    float a, float qw, int e, int p1,
    float* accv, float& den, float& saw)
{
    float vt[16];
    float sc = 0.f;
    float2 f;
    f = h2f2(u0.x); sc = fmaf(q0.x, f.x, sc); vt[0]  = f.y;
    f = h2f2(u0.y); sc = fmaf(q0.y, f.x, sc); vt[1]  = f.y;
    f = h2f2(u0.z); sc = fmaf(q0.z, f.x, sc); vt[2]  = f.y;
    f = h2f2(u0.w); sc = fmaf(q0.w, f.x, sc); vt[3]  = f.y;
    f = h2f2(u1.x); sc = fmaf(q1.x, f.x, sc); vt[4]  = f.y;
    f = h2f2(u1.y); sc = fmaf(q1.y, f.x, sc); vt[5]  = f.y;
    f = h2f2(u1.z); sc = fmaf(q1.z, f.x, sc); vt[6]  = f.y;
    f = h2f2(u1.w); sc = fmaf(q1.w, f.x, sc); vt[7]  = f.y;
    f = h2f2(u2.x); sc = fmaf(q2.x, f.x, sc); vt[8]  = f.y;
    f = h2f2(u2.y); sc = fmaf(q2.y, f.x, sc); vt[9]  = f.y;
    f = h2f2(u2.z); sc = fmaf(q2.z, f.x, sc); vt[10] = f.y;
    f = h2f2(u2.w); sc = fmaf(q2.w, f.x, sc); vt[11] = f.y;
    f = h2f2(u3.x); sc = fmaf(q3.x, f.x, sc); vt[12] = f.y;
    f = h2f2(u3.y); sc = fmaf(q3.y, f.x, sc); vt[13] = f.y;
    f = h2f2(u3.z); sc = fmaf(q3.z, f.x, sc); vt[14] = f.y;
    f = h2f2(u3.w); sc = fmaf(q3.w, f.x, sc); vt[15] = f.y;

    float w = __expf(fmaf(a, qw, sc) * 0.25f);
    if (e >= p1) w = 0.f;
    den += w;
    saw = fmaf(w, a, saw);
    #pragma unroll
    for (int j = 0; j < 16; ++j) accv[j] = fmaf(w, vt[j], accv[j]);
}

#define ATTN_BLOCKS 2048

__global__ __launch_bounds__(256) void node_attn(
    const float* __restrict__ q, const __half* __restrict__ kvh,
    const float* __restrict__ sk, const float* __restrict__ We,
    const int* __restrict__ row_ptr, const int* __restrict__ src_s,
    const float* __restrict__ attr_s,
    float* __restrict__ out, int do_relu, int do_pool,
    const int* __restrict__ batch,
    float* __restrict__ gsum, float* __restrict__ gcnt)
{
    __shared__ float lds[4 * 16 * 68];
    int wid   = threadIdx.x >> 6;
    int lane  = threadIdx.x & 63;
    int eslot = lane & 15;
    int head  = lane >> 4;

    const int NW = ATTN_BLOCKS * 4;
    int node = blockIdx.x * 4 + wid;
    if (node >= NN) return;

    float* buf = lds + wid * (16 * 68);
    const __half* kvbase = kvh + head * 32;
    const float4* wep = (const float4*)(We + head * 16);

    // ---- prologue: fill 3-deep pipeline ----
    int n1 = node + NW;     int n1c = (n1 < NN) ? n1 : node;
    int n2 = node + 2 * NW; int n2c = (n2 < NN) ? n2 : node;
    int p0c = row_ptr[node], p1c = row_ptr[node + 1];
    int p0n = row_ptr[n1c],  p1n = row_ptr[n1c + 1];
    int p0n2 = row_ptr[n2c], p1n2 = row_ptr[n2c + 1];

    int i0 = cidx(p0c + eslot, p0c, p1c);
    int i1 = cidx(p0c + 16 + eslot, p0c, p1c);
    int   s0c = src_s[i0]; float a0c = attr_s[i0];
    int   s1c = src_s[i1]; float a1c = attr_s[i1];
    int j0 = cidx(p0n + eslot, p0n, p1n);
    int j1 = cidx(p0n + 16 + eslot, p0n, p1n);
    int   s0n = src_s[j0]; float a0n = attr_s[j0];
    int   s1n = src_s[j1]; float a1n = attr_s[j1];

    const float4* qp = (const float4*)(q + (size_t)node * 64 + head * 16);
    float4 qc0 = qp[0], qc1 = qp[1], qc2 = qp[2], qc3 = qp[3];
    float skc = sk[(size_t)node * 64 + lane];

    // kv chunk-0 for first node
    const uint4* kvp0 = (const uint4*)(kvbase + (size_t)s0c * 128);
    uint4 u0 = kvp0[0], u1 = kvp0[1], u2 = kvp0[2], u3 = kvp0[3];

    for (;;) {
        int nx1 = node + NW;
        int nx3 = node + 3 * NW;
        int nx1c = (nx1 < NN) ? nx1 : node;
        int nx3c = (nx3 < NN) ? nx3 : node;

        // ---- issue phase (all independent of current compute) ----
        const uint4* kvb = (const uint4*)(kvbase + (size_t)s1c * 128);
        uint4 x0 = kvb[0], x1 = kvb[1], x2 = kvb[2], x3 = kvb[3];
        const uint4* kvn = (const uint4*)(kvbase + (size_t)s0n * 128);
        uint4 un0 = kvn[0], un1 = kvn[1], un2 = kvn[2], un3 = kvn[3];
        int p0n3 = row_ptr[nx3c], p1n3 = row_ptr[nx3c + 1];
        int k0 = cidx(p0n2 + eslot, p0n2, p1n2);
        int k1 = cidx(p0n2 + 16 + eslot, p0n2, p1n2);
        int   s0n2 = src_s[k0]; float a0n2 = attr_s[k0];
        int   s1n2 = src_s[k1]; float a1n2 = attr_s[k1];
        const float4* qpn = (const float4*)(q + (size_t)nx1c * 64 + head * 16);
        float4 qn0 = qpn[0], qn1 = qpn[1], qn2 = qpn[2], qn3 = qpn[3];
        float skn = sk[(size_t)nx1c * 64 + lane];
        float4 w0 = wep[0], w1 = wep[1], w2 = wep[2], w3 = wep[3];
        float wec = We[lane];

        // ---- compute phase ----
        float qw = qc0.x * w0.x;
        qw = fmaf(qc0.y, w0.y, qw); qw = fmaf(qc0.z, w0.z, qw); qw = fmaf(qc0.w, w0.w, qw);
        qw = fmaf(qc1.x, w1.x, qw); qw = fmaf(qc1.y, w1.y, qw); qw = fmaf(qc1.z, w1.z, qw); qw = fmaf(qc1.w, w1.w, qw);
        qw = fmaf(qc2.x, w2.x, qw); qw = fmaf(qc2.y, w2.y, qw); qw = fmaf(qc2.z, w2.z, qw); qw = fmaf(qc2.w, w2.w, qw);
        qw = fmaf(qc3.x, w3.x, qw); qw = fmaf(qc3.y, w3.y, qw); qw = fmaf(qc3.z, w3.z, qw); qw = fmaf(qc3.w, w3.w, qw);

        float accv[16];
        #pragma unroll
        for (int j = 0; j < 16; ++j) accv[j] = 0.f;
        float den = 0.f, saw = 0.f;

        chunk16(u0, u1, u2, u3, qc0, qc1, qc2, qc3,
                a0c, qw, p0c + eslot, p1c, accv, den, saw);
        chunk16(x0, x1, x2, x3, qc0, qc1, qc2, qc3,
                a1c, qw, p0c + 16 + eslot, p1c, accv, den, saw);

        // remainder chunks (deg > 32; rare for Poisson(16))
        #pragma unroll 1
        for (int p = p0c + 32; p < p1c; p += 16) {
            int e = p + eslot;
            int i = cidx(e, p0c, p1c);
            int s = src_s[i];
            float a = attr_s[i];
            const uint4* kr = (const uint4*)(kvbase + (size_t)s * 128);
            uint4 r0 = kr[0], r1 = kr[1], r2 = kr[2], r3 = kr[3];
            chunk16(r0, r1, r2, r3, qc0, qc1, qc2, qc3,
                    a, qw, e, p1c, accv, den, saw);
        }

        // den/saw: reduce across the 16 edge-lanes of this head
        den += __shfl_xor(den, 1); den += __shfl_xor(den, 2);
        den += __shfl_xor(den, 4); den += __shfl_xor(den, 8);
        saw += __shfl_xor(saw, 1); saw += __shfl_xor(saw, 2);
        saw += __shfl_xor(saw, 4); saw += __shfl_xor(saw, 8);

        // acc transpose: (head,edge) partials -> per-channel totals via LDS
        float4* bw = (float4*)(buf + eslot * 68 + head * 16);
        bw[0] = make_float4(accv[0],  accv[1],  accv[2],  accv[3]);
        bw[1] = make_float4(accv[4],  accv[5],  accv[6],  accv[7]);
        bw[2] = make_float4(accv[8],  accv[9],  accv[10], accv[11]);
        bw[3] = make_float4(accv[12], accv[13], accv[14], accv[15]);
        float tot = 0.f;
        #pragma unroll
        for (int e2 = 0; e2 < 16; ++e2) tot += buf[e2 * 68 + lane];

        float o = fmaf(saw, wec, tot) / (den + 1e-16f) + skc;
        if (do_relu) o = fmaxf(o, 0.f);
        out[(size_t)node * 64 + lane] = o;

        if (do_pool) {
            int b = batch[node];
            atomicAdd(&gsum[(size_t)b * 64 + lane], o);
            if (lane == 0) atomicAdd(&gcnt[b], 1.f);
        }

        // ---- rotate pipeline ----
        node = nx1;
        if (node >= NN) break;
        p0c = p0n;  p1c = p1n;
        p0n = p0n2; p1n = p1n2;
        p0n2 = p0n3; p1n2 = p1n3;
        s0c = s0n;  a0c = a0n;  s1c = s1n;  a1c = a1n;
        s0n = s0n2; a0n = a0n2; s1n = s1n2; a1n = a1n2;
        qc0 = qn0; qc1 = qn1; qc2 = qn2; qc3 = qn3;
        skc = skn;
        u0 = un0; u1 = un1; u2 = un2; u3 = un3;
    }
}

// ---------------------------------------------------------------------------
// mean-pool finalize + 3-layer MLP head; one block (128 thr) per graph
// ---------------------------------------------------------------------------
__global__ __launch_bounds__(128) void pool_mlp(
    const float* __restrict__ gsum, const float* __restrict__ gcnt,
    const float* __restrict__ W1, const float* __restrict__ b1,
    const float* __restrict__ W2, const float* __restrict__ b2,
    const float* __restrict__ W3, const float* __restrict__ b3,
    float* __restrict__ out)
{
    __shared__ float g[64];
    __shared__ float h1s[64];
    __shared__ float h2s[16];
    int b = blockIdx.x, t = threadIdx.x;

    if (t < 64) {
        float c = gcnt[b];
        g[t] = gsum[(size_t)b * 64 + t] / fmaxf(c, 1.f);
    }
    __syncthreads();
    if (t < 64) {
        float a = b1[t];
        #pragma unroll
        for (int i = 0; i < 64; ++i) a = fmaf(g[i], W1[i * 64 + t], a);
        h1s[t] = fmaxf(a, 0.f);
    }
    __syncthreads();
    if (t < 16) {
        float a = b2[t];
        #pragma unroll
        for (int i = 0; i < 64; ++i) a = fmaf(h1s[i], W2[i * 16 + t], a);
        h2s[t] = fmaxf(a, 0.f);
    }
    __syncthreads();
    float a = b3[t];
    #pragma unroll
    for (int i = 0; i < 16; ++i) a = fmaf(h2s[i], W3[i * 128 + t], a);
    out[(size_t)b * 128 + t] = a;
}

// ---------------------------------------------------------------------------
extern "C" void kernel_launch(void* const* d_in, const int* in_sizes, int n_in,
                              void* d_out, int out_size, void* d_ws, size_t ws_size,
                              hipStream_t stream) {
    const float* x         = (const float*)d_in[0];
    const float* edge_attr = (const float*)d_in[1];
    const int*   edge_index= (const int*)d_in[2];
    const int*   batch     = (const int*)d_in[3];
    const float* Wq   = (const float*)d_in[4];
    const float* bq   = (const float*)d_in[5];
    const float* Wk   = (const float*)d_in[6];
    const float* bk   = (const float*)d_in[7];
    const float* Wv   = (const float*)d_in[8];
    const float* bv   = (const float*)d_in[9];
    const float* We   = (const float*)d_in[10];
    const float* Wsk  = (const float*)d_in[11];
    const float* bsk  = (const float*)d_in[12];
    const float* W1   = (const float*)d_in[13];
    const float* b1   = (const float*)d_in[14];
    const float* W2   = (const float*)d_in[15];
    const float* b2   = (const float*)d_in[16];
    const float* W3   = (const float*)d_in[17];
    const float* b3   = (const float*)d_in[18];

    float* out        = (float*)d_out;
    float* node_emb   = out;                         // N*64
    float* graph_feat = out + (size_t)NN * 64;       // G*128

    float* wsf    = (float*)d_ws;
    float* q      = wsf;
    float* kvf    = q    + (size_t)NN * 64;          // N*64 dwords: packed half2(k,v)
    float* skp    = kvf  + (size_t)NN * 64;
    float* h      = skp  + (size_t)NN * 64;
    float* attr_s = h    + (size_t)NN * 64;
    int*   src_s  = (int*)(attr_s + EE);
    int*   row_ptr= src_s + EE;
    int*   wpos   = row_ptr + (NN + 1);
    float* gsum   = (float*)(wpos + NN);
    float* gcnt   = gsum + (size_t)GG * 64;
    int*   bsum   = (int*)(gcnt + GG);
    int*   boff   = bsum + 256;
    __half* kvh   = (__half*)kvf;

    // ---- CSR build (dst-sorted edges); reused by all 3 layers ----
    zero_i32<<<(NN + 255) / 256, 256, 0, stream>>>(wpos, NN);
    zero_f32<<<(GG * 64 + GG + 255) / 256, 256, 0, stream>>>(gsum, GG * 64 + GG);
    hist_kernel<<<(EE + 255) / 256, 256, 0, stream>>>(edge_index + EE, wpos);
    scan_partial<<<SCAN_B, 256, 0, stream>>>(wpos, bsum);
    scan_tops<<<1, 256, 0, stream>>>(bsum, boff, row_ptr);
    scan_final<<<SCAN_B, 256, 0, stream>>>(wpos, boff, row_ptr, wpos);
    scatter_kernel<<<(EE + 255) / 256, 256, 0, stream>>>(edge_index, edge_attr,
                                                         wpos, src_s, attr_s);

    int gemm_grid = (NN + 31) / 32;

    const float* layer_in = x;
    for (int l = 0; l < LL; ++l) {
        const float* Wq_l = Wq + (size_t)l * 64 * 64;
        const float* Wk_l = Wk + (size_t)l * 64 * 64;
        const float* Wv_l = Wv + (size_t)l * 64 * 64;
        const float* Ws_l = Wsk + (size_t)l * 64 * 64;
        const float* bq_l = bq + (size_t)l * 64;
        const float* bk_l = bk + (size_t)l * 64;
        const float* bv_l = bv + (size_t)l * 64;
        const float* bs_l = bsk + (size_t)l * 64;
        const float* We_l = We + (size_t)l * 64;

        node_gemm<<<gemm_grid, 256, 0, stream>>>(layer_in,
            Wq_l, bq_l, Wk_l, bk_l, Wv_l, bv_l, Ws_l, bs_l,
            q, kvh, skp);

        int last = (l == LL - 1);
        float* dst_h = last ? node_emb : h;
        node_attn<<<ATTN_BLOCKS, 256, 0, stream>>>(q, kvh, skp, We_l,
            row_ptr, src_s, attr_s,
            dst_h, /*relu=*/!last, /*pool=*/last,
            batch, gsum, gcnt);

        layer_in = h;
    }

    pool_mlp<<<GG, 128, 0, stream>>>(gsum, gcnt, W1, b1, W2, b2, W3, b3, graph_feat);
}

// Round 7
// 492.825 us; speedup vs baseline: 1.1204x; 1.0072x over previous
//
#include <hip/hip_runtime.h>
#include <hip/hip_fp16.h>

#define NN 50000
#define EE 800000
#define LL 3
#define HH 4
#define CC 16
#define DD 64
#define GG 512
#define GRAPH_DIM 128
#define SCAN_B 196   // ceil(NN/256)

// ---------------------------------------------------------------------------
// merged zero: wpos (NN ints) + gsum/gcnt (GG*64+GG floats), one dispatch
// ---------------------------------------------------------------------------
__global__ __launch_bounds__(256) void zero_ws(int* __restrict__ wpos,
                                               float* __restrict__ gs) {
    int i = blockIdx.x * blockDim.x + threadIdx.x;
    int stride = gridDim.x * blockDim.x;
    for (int k = i; k < NN; k += stride) wpos[k] = 0;
    for (int k = i; k < GG * 64 + GG; k += stride) gs[k] = 0.f;
}

// ---------------------------------------------------------------------------
// CSR build: histogram of dst, 3-stage parallel exclusive scan, scatter
// ---------------------------------------------------------------------------
__global__ void hist_kernel(const int* __restrict__ dst, int* __restrict__ counts) {
    int e = blockIdx.x * blockDim.x + threadIdx.x;
    if (e < EE) atomicAdd(&counts[dst[e]], 1);
}

// stage 1: per-block (256 elems) sums
__global__ __launch_bounds__(256) void scan_partial(const int* __restrict__ counts,
                                                    int* __restrict__ bsum) {
    __shared__ int ws[4];
    int b = blockIdx.x, t = threadIdx.x, lane = t & 63, wid = t >> 6;
    int idx = b * 256 + t;
    int x = (idx < NN) ? counts[idx] : 0;
    #pragma unroll
    for (int o = 1; o < 64; o <<= 1) x += __shfl_xor(x, o);
    if (lane == 0) ws[wid] = x;
    __syncthreads();
    if (t == 0) bsum[b] = ws[0] + ws[1] + ws[2] + ws[3];
}

// stage 2: one block scans the 196 block sums (Hillis-Steele over 256 slots)
__global__ __launch_bounds__(256) void scan_tops(const int* __restrict__ bsum,
                                                 int* __restrict__ boff,
                                                 int* __restrict__ row_ptr) {
    __shared__ int tmp[2][256];
    int t = threadIdx.x;
    int v = (t < SCAN_B) ? bsum[t] : 0;
    tmp[0][t] = v;
    __syncthreads();
    int src = 0;
    for (int o = 1; o < 256; o <<= 1) {
        int val = tmp[src][t];
        if (t >= o) val += tmp[src][t - o];
        tmp[src ^ 1][t] = val;
        __syncthreads();
        src ^= 1;
    }
    if (t < SCAN_B) boff[t] = tmp[src][t] - v;   // exclusive
    if (t == 255) row_ptr[NN] = tmp[src][255];   // total = EE
}

// stage 3: local exclusive scan + block offset -> row_ptr & writepos
__global__ __launch_bounds__(256) void scan_final(const int* __restrict__ counts,
                                                  const int* __restrict__ boff,
                                                  int* __restrict__ row_ptr,
                                                  int* __restrict__ wpos) {
    __shared__ int ws[4];
    int b = blockIdx.x, t = threadIdx.x, lane = t & 63, wid = t >> 6;
    int idx = b * 256 + t;
    int v = (idx < NN) ? counts[idx] : 0;
    int x = v;
    #pragma unroll
    for (int o = 1; o < 64; o <<= 1) {
        int y = __shfl_up(x, o);
        if (lane >= o) x += y;
    }
    if (lane == 63) ws[wid] = x;
    __syncthreads();
    int add = boff[b];
    #pragma unroll
    for (int w = 0; w < 4; ++w) add += (w < wid) ? ws[w] : 0;
    int excl = x - v + add;
    if (idx < NN) { row_ptr[idx] = excl; wpos[idx] = excl; }
}

__global__ void scatter_kernel(const int* __restrict__ ei, const float* __restrict__ attr,
                               int* __restrict__ writepos,
                               int* __restrict__ src_s, float* __restrict__ attr_s) {
    int e = blockIdx.x * blockDim.x + threadIdx.x;
    if (e < EE) {
        int s = ei[e];
        int d = ei[EE + e];
        int p = atomicAdd(&writepos[d], 1);
        src_s[p] = s;
        attr_s[p] = attr[e];
    }
}

// ---------------------------------------------------------------------------
// fused node GEMM (R4 version — measured fastest): q = h@Wq+bq (f32);
// sk = h@Ws+bs (f32); kvh[node*64+j] = half2(k_j, v_j) via 2B half stores
// (k-wave / v-wave write disjoint halves of each dword).
// ---------------------------------------------------------------------------
__global__ __launch_bounds__(256) void node_gemm(
    const float* __restrict__ hx,
    const float* __restrict__ Wq, const float* __restrict__ bq,
    const float* __restrict__ Wk, const float* __restrict__ bk,
    const float* __restrict__ Wv, const float* __restrict__ bv,
    const float* __restrict__ Ws, const float* __restrict__ bs,
    float* __restrict__ q, __half* __restrict__ kvh, float* __restrict__ sk)
{
    __shared__ float xs[32 * 64];
    int t = threadIdx.x;
    int node0 = blockIdx.x * 32;

    const float4* src4 = (const float4*)(hx + (size_t)node0 * 64);
    float4* dst4 = (float4*)xs;
    #pragma unroll
    for (int r = 0; r < 2; ++r) {
        int i4 = t + r * 256;
        int node = node0 + (i4 >> 4);
        float4 val = make_float4(0.f, 0.f, 0.f, 0.f);
        if (node < NN) val = src4[i4];
        dst4[i4] = val;
    }
    __syncthreads();

    int mat = t >> 6, j = t & 63;
    const float* W = (mat == 0) ? Wq : (mat == 1) ? Wk : (mat == 2) ? Wv : Ws;
    const float* B = (mat == 0) ? bq : (mat == 1) ? bk : (mat == 2) ? bv : bs;

    float wcol[64];
    #pragma unroll
    for (int i = 0; i < 64; ++i) wcol[i] = W[i * 64 + j];
    float bj = B[j];

    for (int n = 0; n < 32; ++n) {
        int node = node0 + n;
        if (node >= NN) break;
        float acc = bj;
        const float4* xr = (const float4*)(xs + n * 64);
        #pragma unroll
        for (int i4 = 0; i4 < 16; ++i4) {
            float4 xv = xr[i4];
            acc = fmaf(xv.x, wcol[4 * i4 + 0], acc);
            acc = fmaf(xv.y, wcol[4 * i4 + 1], acc);
            acc = fmaf(xv.z, wcol[4 * i4 + 2], acc);
            acc = fmaf(xv.w, wcol[4 * i4 + 3], acc);
        }
        size_t idx = (size_t)node * 64 + j;
        if (mat == 0)      q[idx]  = acc;
        else if (mat == 3) sk[idx] = acc;
        else kvh[idx * 2 + (mat == 2)] = __float2half_rn(acc);
    }
}

// ---------------------------------------------------------------------------
// persistent node-centric attention, cross-node software pipeline (R5):
//   lane = head*16 + edge_slot;  waves grid-stride over nodes.
//   Depth: row_ptr 3-ahead, src/attr 2-ahead, q/sk 1-ahead,
//          kv chunk-0 1-ahead;  kv chunk-1 in-iteration.
//   Grid = 1536 blocks: residency-matched (VGPR 80 -> 6 blocks/CU x 256 CU)
//   so all waves run in a single full-occupancy phase (no ragged tail).
// ---------------------------------------------------------------------------
static __device__ __forceinline__ float2 h2f2(unsigned u) {
    __half2 h = __builtin_bit_cast(__half2, u);
    return __half22float2(h);
}

static __device__ __forceinline__ int cidx(int e, int p0, int p1) {
    int hi = max(p1 - 1, p0);
    int i = min(e, hi);
    return min(i, EE - 1);
}

static __device__ __forceinline__ void chunk16(
    uint4 u0, uint4 u1, uint4 u2, uint4 u3,
    float4 q0, float4 q1, float4 q2, float4 q3,
    float a, float qw, int e, int p1,
    float* accv, float& den, float& saw)
{
    float vt[16];
    float sc = 0.f;
    float2 f;
    f = h2f2(u0.x); sc = fmaf(q0.x, f.x, sc); vt[0]  = f.y;
    f = h2f2(u0.y); sc = fmaf(q0.y, f.x, sc); vt[1]  = f.y;
    f = h2f2(u0.z); sc = fmaf(q0.z, f.x, sc); vt[2]  = f.y;
    f = h2f2(u0.w); sc = fmaf(q0.w, f.x, sc); vt[3]  = f.y;
    f = h2f2(u1.x); sc = fmaf(q1.x, f.x, sc); vt[4]  = f.y;
    f = h2f2(u1.y); sc = fmaf(q1.y, f.x, sc); vt[5]  = f.y;
    f = h2f2(u1.z); sc = fmaf(q1.z, f.x, sc); vt[6]  = f.y;
    f = h2f2(u1.w); sc = fmaf(q1.w, f.x, sc); vt[7]  = f.y;
    f = h2f2(u2.x); sc = fmaf(q2.x, f.x, sc); vt[8]  = f.y;
    f = h2f2(u2.y); sc = fmaf(q2.y, f.x, sc); vt[9]  = f.y;
    f = h2f2(u2.z); sc = fmaf(q2.z, f.x, sc); vt[10] = f.y;
    f = h2f2(u2.w); sc = fmaf(q2.w, f.x, sc); vt[11] = f.y;
    f = h2f2(u3.x); sc = fmaf(q3.x, f.x, sc); vt[12] = f.y;
    f = h2f2(u3.y); sc = fmaf(q3.y, f.x, sc); vt[13] = f.y;
    f = h2f2(u3.z); sc = fmaf(q3.z, f.x, sc); vt[14] = f.y;
    f = h2f2(u3.w); sc = fmaf(q3.w, f.x, sc); vt[15] = f.y;

    float w = __expf(fmaf(a, qw, sc) * 0.25f);
    if (e >= p1) w = 0.f;
    den += w;
    saw = fmaf(w, a, saw);
    #pragma unroll
    for (int j = 0; j < 16; ++j) accv[j] = fmaf(w, vt[j], accv[j]);
}

#define ATTN_BLOCKS 1536

__global__ __launch_bounds__(256) void node_attn(
    const float* __restrict__ q, const __half* __restrict__ kvh,
    const float* __restrict__ sk, const float* __restrict__ We,
    const int* __restrict__ row_ptr, const int* __restrict__ src_s,
    const float* __restrict__ attr_s,
    float* __restrict__ out, int do_relu, int do_pool,
    const int* __restrict__ batch,
    float* __restrict__ gsum, float* __restrict__ gcnt)
{
    __shared__ float lds[4 * 16 * 68];
    int wid   = threadIdx.x >> 6;
    int lane  = threadIdx.x & 63;
    int eslot = lane & 15;
    int head  = lane >> 4;

    const int NW = ATTN_BLOCKS * 4;
    int node = blockIdx.x * 4 + wid;
    if (node >= NN) return;

    float* buf = lds + wid * (16 * 68);
    const __half* kvbase = kvh + head * 32;
    const float4* wep = (const float4*)(We + head * 16);

    // ---- prologue: fill 3-deep pipeline ----
    int n1 = node + NW;     int n1c = (n1 < NN) ? n1 : node;
    int n2 = node + 2 * NW; int n2c = (n2 < NN) ? n2 : node;
    int p0c = row_ptr[node], p1c = row_ptr[node + 1];
    int p0n = row_ptr[n1c],  p1n = row_ptr[n1c + 1];
    int p0n2 = row_ptr[n2c], p1n2 = row_ptr[n2c + 1];

    int i0 = cidx(p0c + eslot, p0c, p1c);
    int i1 = cidx(p0c + 16 + eslot, p0c, p1c);
    int   s0c = src_s[i0]; float a0c = attr_s[i0];
    int   s1c = src_s[i1]; float a1c = attr_s[i1];
    int j0 = cidx(p0n + eslot, p0n, p1n);
    int j1 = cidx(p0n + 16 + eslot, p0n, p1n);
    int   s0n = src_s[j0]; float a0n = attr_s[j0];
    int   s1n = src_s[j1]; float a1n = attr_s[j1];

    const float4* qp = (const float4*)(q + (size_t)node * 64 + head * 16);
    float4 qc0 = qp[0], qc1 = qp[1], qc2 = qp[2], qc3 = qp[3];
    float skc = sk[(size_t)node * 64 + lane];

    // kv chunk-0 for first node
    const uint4* kvp0 = (const uint4*)(kvbase + (size_t)s0c * 128);
    uint4 u0 = kvp0[0], u1 = kvp0[1], u2 = kvp0[2], u3 = kvp0[3];

    for (;;) {
        int nx1 = node + NW;
        int nx3 = node + 3 * NW;
        int nx1c = (nx1 < NN) ? nx1 : node;
        int nx3c = (nx3 < NN) ? nx3 : node;

        // ---- issue phase (all independent of current compute) ----
        const uint4* kvb = (const uint4*)(kvbase + (size_t)s1c * 128);
        uint4 x0 = kvb[0], x1 = kvb[1], x2 = kvb[2], x3 = kvb[3];
        const uint4* kvn = (const uint4*)(kvbase + (size_t)s0n * 128);
        uint4 un0 = kvn[0], un1 = kvn[1], un2 = kvn[2], un3 = kvn[3];
        int p0n3 = row_ptr[nx3c], p1n3 = row_ptr[nx3c + 1];
        int k0 = cidx(p0n2 + eslot, p0n2, p1n2);
        int k1 = cidx(p0n2 + 16 + eslot, p0n2, p1n2);
        int   s0n2 = src_s[k0]; float a0n2 = attr_s[k0];
        int   s1n2 = src_s[k1]; float a1n2 = attr_s[k1];
        const float4* qpn = (const float4*)(q + (size_t)nx1c * 64 + head * 16);
        float4 qn0 = qpn[0], qn1 = qpn[1], qn2 = qpn[2], qn3 = qpn[3];
        float skn = sk[(size_t)nx1c * 64 + lane];
        float4 w0 = wep[0], w1 = wep[1], w2 = wep[2], w3 = wep[3];
        float wec = We[lane];

        // ---- compute phase ----
        float qw = qc0.x * w0.x;
        qw = fmaf(qc0.y, w0.y, qw); qw = fmaf(qc0.z, w0.z, qw); qw = fmaf(qc0.w, w0.w, qw);
        qw = fmaf(qc1.x, w1.x, qw); qw = fmaf(qc1.y, w1.y, qw); qw = fmaf(qc1.z, w1.z, qw); qw = fmaf(qc1.w, w1.w, qw);
        qw = fmaf(qc2.x, w2.x, qw); qw = fmaf(qc2.y, w2.y, qw); qw = fmaf(qc2.z, w2.z, qw); qw = fmaf(qc2.w, w2.w, qw);
        qw = fmaf(qc3.x, w3.x, qw); qw = fmaf(qc3.y, w3.y, qw); qw = fmaf(qc3.z, w3.z, qw); qw = fmaf(qc3.w, w3.w, qw);

        float accv[16];
        #pragma unroll
        for (int j = 0; j < 16; ++j) accv[j] = 0.f;
        float den = 0.f, saw = 0.f;

        chunk16(u0, u1, u2, u3, qc0, qc1, qc2, qc3,
                a0c, qw, p0c + eslot, p1c, accv, den, saw);
        chunk16(x0, x1, x2, x3, qc0, qc1, qc2, qc3,
                a1c, qw, p0c + 16 + eslot, p1c, accv, den, saw);

        // remainder chunks (deg > 32; rare for Poisson(16))
        #pragma unroll 1
        for (int p = p0c + 32; p < p1c; p += 16) {
            int e = p + eslot;
            int i = cidx(e, p0c, p1c);
            int s = src_s[i];
            float a = attr_s[i];
            const uint4* kr = (const uint4*)(kvbase + (size_t)s * 128);
            uint4 r0 = kr[0], r1 = kr[1], r2 = kr[2], r3 = kr[3];
            chunk16(r0, r1, r2, r3, qc0, qc1, qc2, qc3,
                    a, qw, e, p1c, accv, den, saw);
        }

        // den/saw: reduce across the 16 edge-lanes of this head
        den += __shfl_xor(den, 1); den += __shfl_xor(den, 2);
        den += __shfl_xor(den, 4); den += __shfl_xor(den, 8);
        saw += __shfl_xor(saw, 1); saw += __shfl_xor(saw, 2);
        saw += __shfl_xor(saw, 4); saw += __shfl_xor(saw, 8);

        // acc transpose: (head,edge) partials -> per-channel totals via LDS
        float4* bw = (float4*)(buf + eslot * 68 + head * 16);
        bw[0] = make_float4(accv[0],  accv[1],  accv[2],  accv[3]);
        bw[1] = make_float4(accv[4],  accv[5],  accv[6],  accv[7]);
        bw[2] = make_float4(accv[8],  accv[9],  accv[10], accv[11]);
        bw[3] = make_float4(accv[12], accv[13], accv[14], accv[15]);
        float tot = 0.f;
        #pragma unroll
        for (int e2 = 0; e2 < 16; ++e2) tot += buf[e2 * 68 + lane];

        float o = fmaf(saw, wec, tot) / (den + 1e-16f) + skc;
        if (do_relu) o = fmaxf(o, 0.f);
        out[(size_t)node * 64 + lane] = o;

        if (do_pool) {
            int b = batch[node];
            atomicAdd(&gsum[(size_t)b * 64 + lane], o);
            if (lane == 0) atomicAdd(&gcnt[b], 1.f);
        }

        // ---- rotate pipeline ----
        node = nx1;
        if (node >= NN) break;
        p0c = p0n;  p1c = p1n;
        p0n = p0n2; p1n = p1n2;
        p0n2 = p0n3; p1n2 = p1n3;
        s0c = s0n;  a0c = a0n;  s1c = s1n;  a1c = a1n;
        s0n = s0n2; a0n = a0n2; s1n = s1n2; a1n = a1n2;
        qc0 = qn0; qc1 = qn1; qc2 = qn2; qc3 = qn3;
        skc = skn;
        u0 = un0; u1 = un1; u2 = un2; u3 = un3;
    }
}

// ---------------------------------------------------------------------------
// mean-pool finalize + 3-layer MLP head; one block (128 thr) per graph
// ---------------------------------------------------------------------------
__global__ __launch_bounds__(128) void pool_mlp(
    const float* __restrict__ gsum, const float* __restrict__ gcnt,
    const float* __restrict__ W1, const float* __restrict__ b1,
    const float* __restrict__ W2, const float* __restrict__ b2,
    const float* __restrict__ W3, const float* __restrict__ b3,
    float* __restrict__ out)
{
    __shared__ float g[64];
    __shared__ float h1s[64];
    __shared__ float h2s[16];
    int b = blockIdx.x, t = threadIdx.x;

    if (t < 64) {
        float c = gcnt[b];
        g[t] = gsum[(size_t)b * 64 + t] / fmaxf(c, 1.f);
    }
    __syncthreads();
    if (t < 64) {
        float a = b1[t];
        #pragma unroll
        for (int i = 0; i < 64; ++i) a = fmaf(g[i], W1[i * 64 + t], a);
        h1s[t] = fmaxf(a, 0.f);
    }
    __syncthreads();
    if (t < 16) {
        float a = b2[t];
        #pragma unroll
        for (int i = 0; i < 64; ++i) a = fmaf(h1s[i], W2[i * 16 + t], a);
        h2s[t] = fmaxf(a, 0.f);
    }
    __syncthreads();
    float a = b3[t];
    #pragma unroll
    for (int i = 0; i < 16; ++i) a = fmaf(h2s[i], W3[i * 128 + t], a);
    out[(size_t)b * 128 + t] = a;
}

// ---------------------------------------------------------------------------
extern "C" void kernel_launch(void* const* d_in, const int* in_sizes, int n_in,
                              void* d_out, int out_size, void* d_ws, size_t ws_size,
                              hipStream_t stream) {
    const float* x         = (const float*)d_in[0];
    const float* edge_attr = (const float*)d_in[1];
    const int*   edge_index= (const int*)d_in[2];
    const int*   batch     = (const int*)d_in[3];
    const float* Wq   = (const float*)d_in[4];
    const float* bq   = (const float*)d_in[5];
    const float* Wk   = (const float*)d_in[6];
    const float* bk   = (const float*)d_in[7];
    const float* Wv   = (const float*)d_in[8];
    const float* bv   = (const float*)d_in[9];
    const float* We   = (const float*)d_in[10];
    const float* Wsk  = (const float*)d_in[11];
    const float* bsk  = (const float*)d_in[12];
    const float* W1   = (const float*)d_in[13];
    const float* b1   = (const float*)d_in[14];
    const float* W2   = (const float*)d_in[15];
    const float* b2   = (const float*)d_in[16];
    const float* W3   = (const float*)d_in[17];
    const float* b3   = (const float*)d_in[18];

    float* out        = (float*)d_out;
    float* node_emb   = out;                         // N*64
    float* graph_feat = out + (size_t)NN * 64;       // G*128

    float* wsf    = (float*)d_ws;
    float* q      = wsf;
    float* kvf    = q    + (size_t)NN * 64;          // N*64 dwords: packed half2(k,v)
    float* skp    = kvf  + (size_t)NN * 64;
    float* h      = skp  + (size_t)NN * 64;
    float* attr_s = h    + (size_t)NN * 64;
    int*   src_s  = (int*)(attr_s + EE);
    int*   row_ptr= src_s + EE;
    int*   wpos   = row_ptr + (NN + 1);
    float* gsum   = (float*)(wpos + NN);
    float* gcnt   = gsum + (size_t)GG * 64;
    int*   bsum   = (int*)(gcnt + GG);
    int*   boff   = bsum + 256;
    __half* kvh   = (__half*)kvf;

    // ---- CSR build (dst-sorted edges); reused by all 3 layers ----
    zero_ws<<<256, 256, 0, stream>>>(wpos, gsum);
    hist_kernel<<<(EE + 255) / 256, 256, 0, stream>>>(edge_index + EE, wpos);
    scan_partial<<<SCAN_B, 256, 0, stream>>>(wpos, bsum);
    scan_tops<<<1, 256, 0, stream>>>(bsum, boff, row_ptr);
    scan_final<<<SCAN_B, 256, 0, stream>>>(wpos, boff, row_ptr, wpos);
    scatter_kernel<<<(EE + 255) / 256, 256, 0, stream>>>(edge_index, edge_attr,
                                                         wpos, src_s, attr_s);

    int gemm_grid = (NN + 31) / 32;

    const float* layer_in = x;
    for (int l = 0; l < LL; ++l) {
        const float* Wq_l = Wq + (size_t)l * 64 * 64;
        const float* Wk_l = Wk + (size_t)l * 64 * 64;
        const float* Wv_l = Wv + (size_t)l * 64 * 64;
        const float* Ws_l = Wsk + (size_t)l * 64 * 64;
        const float* bq_l = bq + (size_t)l * 64;
        const float* bk_l = bk + (size_t)l * 64;
        const float* bv_l = bv + (size_t)l * 64;
        const float* bs_l = bsk + (size_t)l * 64;
        const float* We_l = We + (size_t)l * 64;

        node_gemm<<<gemm_grid, 256, 0, stream>>>(layer_in,
            Wq_l, bq_l, Wk_l, bk_l, Wv_l, bv_l, Ws_l, bs_l,
            q, kvh, skp);

        int last = (l == LL - 1);
        float* dst_h = last ? node_emb : h;
        node_attn<<<ATTN_BLOCKS, 256, 0, stream>>>(q, kvh, skp, We_l,
            row_ptr, src_s, attr_s,
            dst_h, /*relu=*/!last, /*pool=*/last,
            batch, gsum, gcnt);

        layer_in = h;
    }

    pool_mlp<<<GG, 128, 0, stream>>>(gsum, gcnt, W1, b1, W2, b2, W3, b3, graph_feat);
}

// Round 8
// 448.056 us; speedup vs baseline: 1.2324x; 1.0999x over previous
//
#include <hip/hip_runtime.h>
#include <hip/hip_fp16.h>

#define NN 50000
#define EE 800000
#define LL 3
#define HH 4
#define CC 16
#define DD 64
#define GG 512
#define GRAPH_DIM 128
#define SCAN_B 196   // ceil(NN/256)

typedef __attribute__((ext_vector_type(8))) _Float16 f16x8;
typedef __attribute__((ext_vector_type(4))) float f32x4;

// ---------------------------------------------------------------------------
// merged zero: wpos (NN ints) + gsum/gcnt (GG*64+GG floats), one dispatch
// ---------------------------------------------------------------------------
__global__ __launch_bounds__(256) void zero_ws(int* __restrict__ wpos,
                                               float* __restrict__ gs) {
    int i = blockIdx.x * blockDim.x + threadIdx.x;
    int stride = gridDim.x * blockDim.x;
    for (int k = i; k < NN; k += stride) wpos[k] = 0;
    for (int k = i; k < GG * 64 + GG; k += stride) gs[k] = 0.f;
}

// ---------------------------------------------------------------------------
// CSR build: histogram of dst, 3-stage parallel exclusive scan, scatter
// ---------------------------------------------------------------------------
__global__ void hist_kernel(const int* __restrict__ dst, int* __restrict__ counts) {
    int e = blockIdx.x * blockDim.x + threadIdx.x;
    if (e < EE) atomicAdd(&counts[dst[e]], 1);
}

// stage 1: per-block (256 elems) sums
__global__ __launch_bounds__(256) void scan_partial(const int* __restrict__ counts,
                                                    int* __restrict__ bsum) {
    __shared__ int ws[4];
    int b = blockIdx.x, t = threadIdx.x, lane = t & 63, wid = t >> 6;
    int idx = b * 256 + t;
    int x = (idx < NN) ? counts[idx] : 0;
    #pragma unroll
    for (int o = 1; o < 64; o <<= 1) x += __shfl_xor(x, o);
    if (lane == 0) ws[wid] = x;
    __syncthreads();
    if (t == 0) bsum[b] = ws[0] + ws[1] + ws[2] + ws[3];
}

// stage 2: one block scans the 196 block sums (Hillis-Steele over 256 slots)
__global__ __launch_bounds__(256) void scan_tops(const int* __restrict__ bsum,
                                                 int* __restrict__ boff,
                                                 int* __restrict__ row_ptr) {
    __shared__ int tmp[2][256];
    int t = threadIdx.x;
    int v = (t < SCAN_B) ? bsum[t] : 0;
    tmp[0][t] = v;
    __syncthreads();
    int src = 0;
    for (int o = 1; o < 256; o <<= 1) {
        int val = tmp[src][t];
        if (t >= o) val += tmp[src][t - o];
        tmp[src ^ 1][t] = val;
        __syncthreads();
        src ^= 1;
    }
    if (t < SCAN_B) boff[t] = tmp[src][t] - v;   // exclusive
    if (t == 255) row_ptr[NN] = tmp[src][255];   // total = EE
}

// stage 3: local exclusive scan + block offset -> row_ptr & writepos
__global__ __launch_bounds__(256) void scan_final(const int* __restrict__ counts,
                                                  const int* __restrict__ boff,
                                                  int* __restrict__ row_ptr,
                                                  int* __restrict__ wpos) {
    __shared__ int ws[4];
    int b = blockIdx.x, t = threadIdx.x, lane = t & 63, wid = t >> 6;
    int idx = b * 256 + t;
    int v = (idx < NN) ? counts[idx] : 0;
    int x = v;
    #pragma unroll
    for (int o = 1; o < 64; o <<= 1) {
        int y = __shfl_up(x, o);
        if (lane >= o) x += y;
    }
    if (lane == 63) ws[wid] = x;
    __syncthreads();
    int add = boff[b];
    #pragma unroll
    for (int w = 0; w < 4; ++w) add += (w < wid) ? ws[w] : 0;
    int excl = x - v + add;
    if (idx < NN) { row_ptr[idx] = excl; wpos[idx] = excl; }
}

__global__ void scatter_kernel(const int* __restrict__ ei, const float* __restrict__ attr,
                               int* __restrict__ writepos,
                               int* __restrict__ src_s, float* __restrict__ attr_s) {
    int e = blockIdx.x * blockDim.x + threadIdx.x;
    if (e < EE) {
        int s = ei[e];
        int d = ei[EE + e];
        int p = atomicAdd(&writepos[d], 1);
        src_s[p] = s;
        attr_s[p] = attr[e];
    }
}

// ---------------------------------------------------------------------------
// MFMA node GEMM: one block = 64 nodes, 4 waves; wave w computes mat w
// (0=q, 1=k, 2=v, 3=skip) as a 64x64 f16-input / f32-accum MFMA tile.
//   A (h tile, fp32->fp16) loaded per-lane from global (L1/L2-hot, 16 KB);
//   B (W) fragment loads: 8 rows x stride-64, converted to fp16;
//   bias folded into C-init.  32 x mfma_f32_16x16x32_f16 per wave.
// Fragment layouts (gfx950): A/B: k=(lane>>4)*8+j, row/col=lane&15;
//                            C/D: col=lane&15, row=(lane>>4)*4+reg.
// k/v waves write packed half2 kvh via disjoint 2B half stores (R4 pattern).
// ---------------------------------------------------------------------------
__global__ __launch_bounds__(256) void node_gemm(
    const float* __restrict__ hx,
    const float* __restrict__ Wq, const float* __restrict__ bq,
    const float* __restrict__ Wk, const float* __restrict__ bk,
    const float* __restrict__ Wv, const float* __restrict__ bv,
    const float* __restrict__ Ws, const float* __restrict__ bs,
    float* __restrict__ q, __half* __restrict__ kvh, float* __restrict__ sk)
{
    int wave = threadIdx.x >> 6;
    int lane = threadIdx.x & 63;
    int l15 = lane & 15, lg = lane >> 4;
    int node0 = blockIdx.x * 64;

    const float* W  = (wave == 0) ? Wq : (wave == 1) ? Wk : (wave == 2) ? Wv : Ws;
    const float* Bv = (wave == 0) ? bq : (wave == 1) ? bk : (wave == 2) ? bv : bs;

    // A fragments [mtile][kstep]: lane holds h[row=mt*16+l15][k=ks*32+lg*8 ..+8]
    f16x8 af[4][2];
    #pragma unroll
    for (int mt = 0; mt < 4; ++mt) {
        int row = node0 + mt * 16 + l15;
        row = min(row, NN - 1);
        const float4* hp = (const float4*)(hx + (size_t)row * 64);
        #pragma unroll
        for (int ks = 0; ks < 2; ++ks) {
            float4 a0 = hp[ks * 8 + lg * 2];
            float4 a1 = hp[ks * 8 + lg * 2 + 1];
            f16x8 f;
            f[0] = (_Float16)a0.x; f[1] = (_Float16)a0.y;
            f[2] = (_Float16)a0.z; f[3] = (_Float16)a0.w;
            f[4] = (_Float16)a1.x; f[5] = (_Float16)a1.y;
            f[6] = (_Float16)a1.z; f[7] = (_Float16)a1.w;
            af[mt][ks] = f;
        }
    }

    // B fragments [ntile][kstep]: lane holds W[k=ks*32+lg*8+j][col=nt*16+l15]
    f16x8 bf[4][2];
    #pragma unroll
    for (int nt = 0; nt < 4; ++nt) {
        #pragma unroll
        for (int ks = 0; ks < 2; ++ks) {
            const float* wp = W + (size_t)(ks * 32 + lg * 8) * 64 + nt * 16 + l15;
            f16x8 f;
            #pragma unroll
            for (int j = 0; j < 8; ++j) f[j] = (_Float16)wp[j * 64];
            bf[nt][ks] = f;
        }
    }

    // acc init with bias (C/D col = lane&15)
    f32x4 acc[4][4];
    #pragma unroll
    for (int nt = 0; nt < 4; ++nt) {
        float b = Bv[nt * 16 + l15];
        #pragma unroll
        for (int mt = 0; mt < 4; ++mt) {
            acc[mt][nt][0] = b; acc[mt][nt][1] = b;
            acc[mt][nt][2] = b; acc[mt][nt][3] = b;
        }
    }

    #pragma unroll
    for (int mt = 0; mt < 4; ++mt)
        #pragma unroll
        for (int nt = 0; nt < 4; ++nt)
            #pragma unroll
            for (int ks = 0; ks < 2; ++ks)
                acc[mt][nt] = __builtin_amdgcn_mfma_f32_16x16x32_f16(
                    af[mt][ks], bf[nt][ks], acc[mt][nt], 0, 0, 0);

    // store: node = node0 + mt*16 + lg*4 + r, col = nt*16 + l15
    #pragma unroll
    for (int mt = 0; mt < 4; ++mt) {
        #pragma unroll
        for (int r = 0; r < 4; ++r) {
            int node = node0 + mt * 16 + lg * 4 + r;
            if (node < NN) {
                size_t nb = (size_t)node * 64;
                #pragma unroll
                for (int nt = 0; nt < 4; ++nt) {
                    int col = nt * 16 + l15;
                    float v = acc[mt][nt][r];
                    if (wave == 0)      q[nb + col] = v;
                    else if (wave == 3) sk[nb + col] = v;
                    else kvh[(nb + col) * 2 + (wave == 2)] = __float2half_rn(v);
                }
            }
        }
    }
}

// ---------------------------------------------------------------------------
// persistent node-centric attention, cross-node software pipeline (R5/R7):
//   lane = head*16 + edge_slot;  waves grid-stride over nodes.
//   Depth: row_ptr 3-ahead, src/attr 2-ahead, q/sk 1-ahead,
//          kv chunk-0 1-ahead;  kv chunk-1 in-iteration.
//   Grid = 1536 blocks: residency-matched (VGPR 80 -> 6 blocks/CU x 256 CU).
// ---------------------------------------------------------------------------
static __device__ __forceinline__ float2 h2f2(unsigned u) {
    __half2 h = __builtin_bit_cast(__half2, u);
    return __half22float2(h);
}

static __device__ __forceinline__ int cidx(int e, int p0, int p1) {
    int hi = max(p1 - 1, p0);
    int i = min(e, hi);
    return min(i, EE - 1);
}

static __device__ __forceinline__ void chunk16(
    uint4 u0, uint4 u1, uint4 u2, uint4 u3,
    float4 q0, float4 q1, float4 q2, float4 q3,
    float a, float qw, int e, int p1,
    float* accv, float& den, float& saw)
{
    float vt[16];
    float sc = 0.f;
    float2 f;
    f = h2f2(u0.x); sc = fmaf(q0.x, f.x, sc); vt[0]  = f.y;
    f = h2f2(u0.y); sc = fmaf(q0.y, f.x, sc); vt[1]  = f.y;
    f = h2f2(u0.z); sc = fmaf(q0.z, f.x, sc); vt[2]  = f.y;
    f = h2f2(u0.w); sc = fmaf(q0.w, f.x, sc); vt[3]  = f.y;
    f = h2f2(u1.x); sc = fmaf(q1.x, f.x, sc); vt[4]  = f.y;
    f = h2f2(u1.y); sc = fmaf(q1.y, f.x, sc); vt[5]  = f.y;
    f = h2f2(u1.z); sc = fmaf(q1.z, f.x, sc); vt[6]  = f.y;
    f = h2f2(u1.w); sc = fmaf(q1.w, f.x, sc); vt[7]  = f.y;
    f = h2f2(u2.x); sc = fmaf(q2.x, f.x, sc); vt[8]  = f.y;
    f = h2f2(u2.y); sc = fmaf(q2.y, f.x, sc); vt[9]  = f.y;
    f = h2f2(u2.z); sc = fmaf(q2.z, f.x, sc); vt[10] = f.y;
    f = h2f2(u2.w); sc = fmaf(q2.w, f.x, sc); vt[11] = f.y;
    f = h2f2(u3.x); sc = fmaf(q3.x, f.x, sc); vt[12] = f.y;
    f = h2f2(u3.y); sc = fmaf(q3.y, f.x, sc); vt[13] = f.y;
    f = h2f2(u3.z); sc = fmaf(q3.z, f.x, sc); vt[14] = f.y;
    f = h2f2(u3.w); sc = fmaf(q3.w, f.x, sc); vt[15] = f.y;

    float w = __expf(fmaf(a, qw, sc) * 0.25f);
    if (e >= p1) w = 0.f;
    den += w;
    saw = fmaf(w, a, saw);
    #pragma unroll
    for (int j = 0; j < 16; ++j) accv[j] = fmaf(w, vt[j], accv[j]);
}

#define ATTN_BLOCKS 1536

__global__ __launch_bounds__(256) void node_attn(
    const float* __restrict__ q, const __half* __restrict__ kvh,
    const float* __restrict__ sk, const float* __restrict__ We,
    const int* __restrict__ row_ptr, const int* __restrict__ src_s,
    const float* __restrict__ attr_s,
    float* __restrict__ out, int do_relu, int do_pool,
    const int* __restrict__ batch,
    float* __restrict__ gsum, float* __restrict__ gcnt)
{
    __shared__ float lds[4 * 16 * 68];
    int wid   = threadIdx.x >> 6;
    int lane  = threadIdx.x & 63;
    int eslot = lane & 15;
    int head  = lane >> 4;

    const int NW = ATTN_BLOCKS * 4;
    int node = blockIdx.x * 4 + wid;
    if (node >= NN) return;

    float* buf = lds + wid * (16 * 68);
    const __half* kvbase = kvh + head * 32;
    const float4* wep = (const float4*)(We + head * 16);

    // ---- prologue: fill 3-deep pipeline ----
    int n1 = node + NW;     int n1c = (n1 < NN) ? n1 : node;
    int n2 = node + 2 * NW; int n2c = (n2 < NN) ? n2 : node;
    int p0c = row_ptr[node], p1c = row_ptr[node + 1];
    int p0n = row_ptr[n1c],  p1n = row_ptr[n1c + 1];
    int p0n2 = row_ptr[n2c], p1n2 = row_ptr[n2c + 1];

    int i0 = cidx(p0c + eslot, p0c, p1c);
    int i1 = cidx(p0c + 16 + eslot, p0c, p1c);
    int   s0c = src_s[i0]; float a0c = attr_s[i0];
    int   s1c = src_s[i1]; float a1c = attr_s[i1];
    int j0 = cidx(p0n + eslot, p0n, p1n);
    int j1 = cidx(p0n + 16 + eslot, p0n, p1n);
    int   s0n = src_s[j0]; float a0n = attr_s[j0];
    int   s1n = src_s[j1]; float a1n = attr_s[j1];

    const float4* qp = (const float4*)(q + (size_t)node * 64 + head * 16);
    float4 qc0 = qp[0], qc1 = qp[1], qc2 = qp[2], qc3 = qp[3];
    float skc = sk[(size_t)node * 64 + lane];

    // kv chunk-0 for first node
    const uint4* kvp0 = (const uint4*)(kvbase + (size_t)s0c * 128);
    uint4 u0 = kvp0[0], u1 = kvp0[1], u2 = kvp0[2], u3 = kvp0[3];

    for (;;) {
        int nx1 = node + NW;
        int nx3 = node + 3 * NW;
        int nx1c = (nx1 < NN) ? nx1 : node;
        int nx3c = (nx3 < NN) ? nx3 : node;

        // ---- issue phase (all independent of current compute) ----
        const uint4* kvb = (const uint4*)(kvbase + (size_t)s1c * 128);
        uint4 x0 = kvb[0], x1 = kvb[1], x2 = kvb[2], x3 = kvb[3];
        const uint4* kvn = (const uint4*)(kvbase + (size_t)s0n * 128);
        uint4 un0 = kvn[0], un1 = kvn[1], un2 = kvn[2], un3 = kvn[3];
        int p0n3 = row_ptr[nx3c], p1n3 = row_ptr[nx3c + 1];
        int k0 = cidx(p0n2 + eslot, p0n2, p1n2);
        int k1 = cidx(p0n2 + 16 + eslot, p0n2, p1n2);
        int   s0n2 = src_s[k0]; float a0n2 = attr_s[k0];
        int   s1n2 = src_s[k1]; float a1n2 = attr_s[k1];
        const float4* qpn = (const float4*)(q + (size_t)nx1c * 64 + head * 16);
        float4 qn0 = qpn[0], qn1 = qpn[1], qn2 = qpn[2], qn3 = qpn[3];
        float skn = sk[(size_t)nx1c * 64 + lane];
        float4 w0 = wep[0], w1 = wep[1], w2 = wep[2], w3 = wep[3];
        float wec = We[lane];

        // ---- compute phase ----
        float qw = qc0.x * w0.x;
        qw = fmaf(qc0.y, w0.y, qw); qw = fmaf(qc0.z, w0.z, qw); qw = fmaf(qc0.w, w0.w, qw);
        qw = fmaf(qc1.x, w1.x, qw); qw = fmaf(qc1.y, w1.y, qw); qw = fmaf(qc1.z, w1.z, qw); qw = fmaf(qc1.w, w1.w, qw);
        qw = fmaf(qc2.x, w2.x, qw); qw = fmaf(qc2.y, w2.y, qw); qw = fmaf(qc2.z, w2.z, qw); qw = fmaf(qc2.w, w2.w, qw);
        qw = fmaf(qc3.x, w3.x, qw); qw = fmaf(qc3.y, w3.y, qw); qw = fmaf(qc3.z, w3.z, qw); qw = fmaf(qc3.w, w3.w, qw);

        float accv[16];
        #pragma unroll
        for (int j = 0; j < 16; ++j) accv[j] = 0.f;
        float den = 0.f, saw = 0.f;

        chunk16(u0, u1, u2, u3, qc0, qc1, qc2, qc3,
                a0c, qw, p0c + eslot, p1c, accv, den, saw);
        chunk16(x0, x1, x2, x3, qc0, qc1, qc2, qc3,
                a1c, qw, p0c + 16 + eslot, p1c, accv, den, saw);

        // remainder chunks (deg > 32; rare for Poisson(16))
        #pragma unroll 1
        for (int p = p0c + 32; p < p1c; p += 16) {
            int e = p + eslot;
            int i = cidx(e, p0c, p1c);
            int s = src_s[i];
            float a = attr_s[i];
            const uint4* kr = (const uint4*)(kvbase + (size_t)s * 128);
            uint4 r0 = kr[0], r1 = kr[1], r2 = kr[2], r3 = kr[3];
            chunk16(r0, r1, r2, r3, qc0, qc1, qc2, qc3,
                    a, qw, e, p1c, accv, den, saw);
        }

        // den/saw: reduce across the 16 edge-lanes of this head
        den += __shfl_xor(den, 1); den += __shfl_xor(den, 2);
        den += __shfl_xor(den, 4); den += __shfl_xor(den, 8);
        saw += __shfl_xor(saw, 1); saw += __shfl_xor(saw, 2);
        saw += __shfl_xor(saw, 4); saw += __shfl_xor(saw, 8);

        // acc transpose: (head,edge) partials -> per-channel totals via LDS
        float4* bw = (float4*)(buf + eslot * 68 + head * 16);
        bw[0] = make_float4(accv[0],  accv[1],  accv[2],  accv[3]);
        bw[1] = make_float4(accv[4],  accv[5],  accv[6],  accv[7]);
        bw[2] = make_float4(accv[8],  accv[9],  accv[10], accv[11]);
        bw[3] = make_float4(accv[12], accv[13], accv[14], accv[15]);
        float tot = 0.f;
        #pragma unroll
        for (int e2 = 0; e2 < 16; ++e2) tot += buf[e2 * 68 + lane];

        float o = fmaf(saw, wec, tot) / (den + 1e-16f) + skc;
        if (do_relu) o = fmaxf(o, 0.f);
        out[(size_t)node * 64 + lane] = o;

        if (do_pool) {
            int b = batch[node];
            atomicAdd(&gsum[(size_t)b * 64 + lane], o);
            if (lane == 0) atomicAdd(&gcnt[b], 1.f);
        }

        // ---- rotate pipeline ----
        node = nx1;
        if (node >= NN) break;
        p0c = p0n;  p1c = p1n;
        p0n = p0n2; p1n = p1n2;
        p0n2 = p0n3; p1n2 = p1n3;
        s0c = s0n;  a0c = a0n;  s1c = s1n;  a1c = a1n;
        s0n = s0n2; a0n = a0n2; s1n = s1n2; a1n = a1n2;
        qc0 = qn0; qc1 = qn1; qc2 = qn2; qc3 = qn3;
        skc = skn;
        u0 = un0; u1 = un1; u2 = un2; u3 = un3;
    }
}

// ---------------------------------------------------------------------------
// mean-pool finalize + 3-layer MLP head; one block (128 thr) per graph
// ---------------------------------------------------------------------------
__global__ __launch_bounds__(128) void pool_mlp(
    const float* __restrict__ gsum, const float* __restrict__ gcnt,
    const float* __restrict__ W1, const float* __restrict__ b1,
    const float* __restrict__ W2, const float* __restrict__ b2,
    const float* __restrict__ W3, const float* __restrict__ b3,
    float* __restrict__ out)
{
    __shared__ float g[64];
    __shared__ float h1s[64];
    __shared__ float h2s[16];
    int b = blockIdx.x, t = threadIdx.x;

    if (t < 64) {
        float c = gcnt[b];
        g[t] = gsum[(size_t)b * 64 + t] / fmaxf(c, 1.f);
    }
    __syncthreads();
    if (t < 64) {
        float a = b1[t];
        #pragma unroll
        for (int i = 0; i < 64; ++i) a = fmaf(g[i], W1[i * 64 + t], a);
        h1s[t] = fmaxf(a, 0.f);
    }
    __syncthreads();
    if (t < 16) {
        float a = b2[t];
        #pragma unroll
        for (int i = 0; i < 64; ++i) a = fmaf(h1s[i], W2[i * 16 + t], a);
        h2s[t] = fmaxf(a, 0.f);
    }
    __syncthreads();
    float a = b3[t];
    #pragma unroll
    for (int i = 0; i < 16; ++i) a = fmaf(h2s[i], W3[i * 128 + t], a);
    out[(size_t)b * 128 + t] = a;
}

// ---------------------------------------------------------------------------
extern "C" void kernel_launch(void* const* d_in, const int* in_sizes, int n_in,
                              void* d_out, int out_size, void* d_ws, size_t ws_size,
                              hipStream_t stream) {
    const float* x         = (const float*)d_in[0];
    const float* edge_attr = (const float*)d_in[1];
    const int*   edge_index= (const int*)d_in[2];
    const int*   batch     = (const int*)d_in[3];
    const float* Wq   = (const float*)d_in[4];
    const float* bq   = (const float*)d_in[5];
    const float* Wk   = (const float*)d_in[6];
    const float* bk   = (const float*)d_in[7];
    const float* Wv   = (const float*)d_in[8];
    const float* bv   = (const float*)d_in[9];
    const float* We   = (const float*)d_in[10];
    const float* Wsk  = (const float*)d_in[11];
    const float* bsk  = (const float*)d_in[12];
    const float* W1   = (const float*)d_in[13];
    const float* b1   = (const float*)d_in[14];
    const float* W2   = (const float*)d_in[15];
    const float* b2   = (const float*)d_in[16];
    const float* W3   = (const float*)d_in[17];
    const float* b3   = (const float*)d_in[18];

    float* out        = (float*)d_out;
    float* node_emb   = out;                         // N*64
    float* graph_feat = out + (size_t)NN * 64;       // G*128

    float* wsf    = (float*)d_ws;
    float* q      = wsf;
    float* kvf    = q    + (size_t)NN * 64;          // N*64 dwords: packed half2(k,v)
    float* skp    = kvf  + (size_t)NN * 64;
    float* h      = skp  + (size_t)NN * 64;
    float* attr_s = h    + (size_t)NN * 64;
    int*   src_s  = (int*)(attr_s + EE);
    int*   row_ptr= src_s + EE;
    int*   wpos   = row_ptr + (NN + 1);
    float* gsum   = (float*)(wpos + NN);
    float* gcnt   = gsum + (size_t)GG * 64;
    int*   bsum   = (int*)(gcnt + GG);
    int*   boff   = bsum + 256;
    __half* kvh   = (__half*)kvf;

    // ---- CSR build (dst-sorted edges); reused by all 3 layers ----
    zero_ws<<<256, 256, 0, stream>>>(wpos, gsum);
    hist_kernel<<<(EE + 255) / 256, 256, 0, stream>>>(edge_index + EE, wpos);
    scan_partial<<<SCAN_B, 256, 0, stream>>>(wpos, bsum);
    scan_tops<<<1, 256, 0, stream>>>(bsum, boff, row_ptr);
    scan_final<<<SCAN_B, 256, 0, stream>>>(wpos, boff, row_ptr, wpos);
    scatter_kernel<<<(EE + 255) / 256, 256, 0, stream>>>(edge_index, edge_attr,
                                                         wpos, src_s, attr_s);

    int gemm_grid = (NN + 63) / 64;

    const float* layer_in = x;
    for (int l = 0; l < LL; ++l) {
        const float* Wq_l = Wq + (size_t)l * 64 * 64;
        const float* Wk_l = Wk + (size_t)l * 64 * 64;
        const float* Wv_l = Wv + (size_t)l * 64 * 64;
        const float* Ws_l = Wsk + (size_t)l * 64 * 64;
        const float* bq_l = bq + (size_t)l * 64;
        const float* bk_l = bk + (size_t)l * 64;
        const float* bv_l = bv + (size_t)l * 64;
        const float* bs_l = bsk + (size_t)l * 64;
        const float* We_l = We + (size_t)l * 64;

        node_gemm<<<gemm_grid, 256, 0, stream>>>(layer_in,
            Wq_l, bq_l, Wk_l, bk_l, Wv_l, bv_l, Ws_l, bs_l,
            q, kvh, skp);

        int last = (l == LL - 1);
        float* dst_h = last ? node_emb : h;
        node_attn<<<ATTN_BLOCKS, 256, 0, stream>>>(q, kvh, skp, We_l,
            row_ptr, src_s, attr_s,
            dst_h, /*relu=*/!last, /*pool=*/last,
            batch, gsum, gcnt);

        layer_in = h;
    }

    pool_mlp<<<GG, 128, 0, stream>>>(gsum, gcnt, W1, b1, W2, b2, W3, b3, graph_feat);
}